// Round 6
// baseline (198.215 us; speedup 1.0000x reference)
//
#include <hip/hip_runtime.h>
#include <hip/hip_bf16.h>

// ScaledDotProductAttention B=2,H=16,S=2048,D=64 causal, f32 in/out (probed).
// v15: v14 + register ping-pong prefetch. r5 post-mortem: v14's
// launch_bounds(64,3) capped VGPR at 72 -> no room for next-tile frags ->
// compiler emitted load->wait->compute strictly serial; each iter ate full
// L2 latency naked (chain ~7000cyc vs ~500cyc pipe work = 15% efficiency,
// all pipes idle: VALU 12 / Mfma 6.5 / HBM 4 / conflicts 0).
//  - Two fragment buffer sets (A/B), loop unrolled by 2:
//    {load B(kt+1); compute A(kt); load A(kt+2); compute B(kt+1)}.
//    Tile kt+1's 16 dwordx4 loads fly during tile kt's MFMA+exp2.
//  - launch_bounds(64,2): VGPR cap 256 (~230 used) -> 2 waves/SIMD,
//    8 independent waves/CU, no barriers, no LDS, self-paced.
//  - prep kernel, decode (4 bh/XCD, LPT long/short interleave), body math
//    (no-max exp2 softmax, sigma PV, CSC in Q), epilogue: verbatim v14
//    (passed).
// L2-BW floor ~17us; predict attn 25-40us (was 101).

typedef __attribute__((ext_vector_type(8))) short  s8v;   // 8 x bf16
typedef __attribute__((ext_vector_type(4))) float  f4v;   // MFMA acc
typedef __attribute__((ext_vector_type(4))) unsigned int u4v;

#define SEQ 2048
#define DH  64
#define BHN 32
#define CSC 0.18033688f   // (1/sqrt(64)) * log2(e)

#if __has_builtin(__builtin_amdgcn_exp2f)
#define EXP2(x) __builtin_amdgcn_exp2f(x)
#else
#define EXP2(x) exp2f(x)
#endif

__device__ __forceinline__ unsigned short f2bf(float x) {
  union { float f; unsigned int u; } v; v.f = x;
  return (unsigned short)((v.u + 0x7fffu + ((v.u >> 16) & 1u)) >> 16);  // RNE
}
__device__ __forceinline__ float bf2f(unsigned short x) {
  union { unsigned int u; float f; } v; v.u = ((unsigned int)x) << 16;
  return v.f;
}
__device__ __forceinline__ int pack_bf2(float a, float b) {
  union { __hip_bfloat162 h; int i; } u;
  u.h = __float22bfloat162_rn(make_float2(a, b));   // a->low, b->high
  return u.i;
}
__device__ __forceinline__ bool probe_is_f32(const unsigned short* p) {
  const unsigned e = (p[threadIdx.x & 63] >> 7) & 0xFFu;
  return __ballot(e >= 0x89u) != 0ULL;
}
__device__ __forceinline__ s8v cvt8(const float* p) {
  float4 a = *(const float4*)p;
  float4 b = *(const float4*)(p + 4);
  s8v r;
  r[0] = (short)f2bf(a.x); r[1] = (short)f2bf(a.y);
  r[2] = (short)f2bf(a.z); r[3] = (short)f2bf(a.w);
  r[4] = (short)f2bf(b.x); r[5] = (short)f2bf(b.y);
  r[6] = (short)f2bf(b.z); r[7] = (short)f2bf(b.w);
  return r;
}
__device__ __forceinline__ s8v cvt8s(const float* p, float s) {
  float4 a = *(const float4*)p;
  float4 b = *(const float4*)(p + 4);
  s8v r;
  r[0] = (short)f2bf(a.x * s); r[1] = (short)f2bf(a.y * s);
  r[2] = (short)f2bf(a.z * s); r[3] = (short)f2bf(a.w * s);
  r[4] = (short)f2bf(b.x * s); r[5] = (short)f2bf(b.y * s);
  r[6] = (short)f2bf(b.z * s); r[7] = (short)f2bf(b.w * s);
  return r;
}

// ---- pre-pass (v10-verified): z=0 K->bf16 (same layout); z=1 V->Vt chunked ----
// Vt layout per 64-key tile, row d: 64 shorts in chunk order; chunk c=kc*4+quad
// holds keys {32kc+4quad+0..3, 32kc+16+4quad+0..3} -> PV B-frag = one 16B read.
__global__ __launch_bounds__(256) void prep_kernel(
    const void* __restrict__ Kv, const void* __restrict__ Vv,
    unsigned short* __restrict__ Kbf, unsigned short* __restrict__ Vt) {
  const int bh = blockIdx.y;
  const int s0 = blockIdx.x * 64;
  const int t  = threadIdx.x;
  if (blockIdx.z == 0) {
    const unsigned short* K16 = (const unsigned short*)Kv;
    const float*          KF  = (const float*)Kv;
    const bool isF32 = probe_is_f32(K16);
    const int sr = t >> 2, c0 = (t & 3) * 16;
    const size_t base = ((size_t)(bh * SEQ + s0 + sr)) * DH + c0;
    s8v a0, a1;
    if (!isF32) { a0 = *(const s8v*)(K16 + base); a1 = *(const s8v*)(K16 + base + 8); }
    else        { a0 = cvt8(KF + base);           a1 = cvt8(KF + base + 8); }
    *(s8v*)(Kbf + base)     = a0;
    *(s8v*)(Kbf + base + 8) = a1;
  } else {
    __shared__ __align__(16) unsigned short T[64][72];
    const unsigned short* V16 = (const unsigned short*)Vv;
    const float*          VF  = (const float*)Vv;
    const bool isF32 = probe_is_f32(V16);
    {
      const int sr = t >> 2, c0 = (t & 3) * 16;
      const size_t base = ((size_t)(bh * SEQ + s0 + sr)) * DH + c0;
      s8v a0, a1;
      if (!isF32) { a0 = *(const s8v*)(V16 + base); a1 = *(const s8v*)(V16 + base + 8); }
      else        { a0 = cvt8(VF + base);           a1 = cvt8(VF + base + 8); }
      *(s8v*)&T[sr][c0]     = a0;
      *(s8v*)&T[sr][c0 + 8] = a1;
    }
    __syncthreads();
    {
      const int d  = t & 63;
      const int hs = t >> 6;            // 0..3 -> chunks 2hs, 2hs+1
      unsigned short* dst = Vt + (size_t)bh * SEQ * DH + (size_t)s0 * 64
                          + (size_t)d * 64 + hs * 16;
#pragma unroll
      for (int cc = 0; cc < 2; ++cc) {
        const int c  = hs * 2 + cc;
        const int kA = (c >> 2) * 32 + (c & 3) * 4;  // base key of chunk
        unsigned int wb[4];
        wb[0] = (unsigned int)T[kA + 0][d]  | ((unsigned int)T[kA + 1][d]  << 16);
        wb[1] = (unsigned int)T[kA + 2][d]  | ((unsigned int)T[kA + 3][d]  << 16);
        wb[2] = (unsigned int)T[kA + 16][d] | ((unsigned int)T[kA + 17][d] << 16);
        wb[3] = (unsigned int)T[kA + 18][d] | ((unsigned int)T[kA + 19][d] << 16);
        u4v q = { wb[0], wb[1], wb[2], wb[3] };
        *(u4v*)(dst + cc * 8) = q;
      }
    }
  }
}

// ---- main: barrier-free flash attention, 1 wave = 32 q-rows, no LDS,
// register ping-pong prefetch of next key-tile ----
__global__ __launch_bounds__(64, 2) void attn_kernel(
    const void* __restrict__ Qv, const unsigned short* __restrict__ Kbf,
    const unsigned short* __restrict__ Vt, void* __restrict__ Outv) {
  const unsigned short* Q16 = (const unsigned short*)Qv;
  const float*          QF  = (const float*)Qv;
  const bool isF32 = probe_is_f32(Q16);

  // decode: blk[2:0]=xcd, blk[4:3]=bh-sub (4 bh per XCD L2), blk[10:5]=i.
  // even i = long blocks (qb 63..32), odd i = short (qb 0..31): LPT-ish.
  const int blk = blockIdx.x;
  const int bh  = (blk & 7) * 4 + ((blk >> 3) & 3);
  const int i   = blk >> 5;                            // 0..63
  const int qb  = (i & 1) ? ((i - 1) >> 1) : (63 - (i >> 1));

  const int lane = threadIdx.x & 63;
  const int quad = lane >> 4;
  const int c16  = lane & 15;
  const int q0   = qb * 32;                            // this wave's 32 q-rows
  const int ntiles = (qb >> 1) + 1;                    // 64-key tiles

  const size_t bh_off = (size_t)bh * SEQ * DH;

  // Q fragments: 2 row-halves x 2 k-chunks, prescaled by CSC
  s8v aq[2][2];
#pragma unroll
  for (int h = 0; h < 2; ++h)
#pragma unroll
    for (int kc = 0; kc < 2; ++kc) {
      const size_t idx = bh_off + (size_t)(q0 + h * 16 + c16) * DH + kc * 32 + quad * 8;
      if (isF32) aq[h][kc] = cvt8s(QF + idx, CSC);
      else {
        s8v aa = *(const s8v*)(Q16 + idx);
#pragma unroll
        for (int t = 0; t < 8; ++t)
          aa[t] = (short)f2bf(bf2f((unsigned short)aa[t]) * CSC);
        aq[h][kc] = aa;
      }
    }

  f4v o[2][4];
  float l[2] = {0.f, 0.f};
#pragma unroll
  for (int h = 0; h < 2; ++h)
#pragma unroll
    for (int i2 = 0; i2 < 4; ++i2) { f4v z = {0.f, 0.f, 0.f, 0.f}; o[h][i2] = z; }

  // per-lane fragment base pointers (tile stride = 64 rows * 64 = 4096 shorts)
  const unsigned short* kp = Kbf + bh_off + (size_t)c16 * DH + quad * 8;
  const unsigned short* vp = Vt  + bh_off + (size_t)c16 * 64 + quad * 8;

  auto load_tile = [&](s8v (&kb)[4][2], s8v (&vb)[4][2], int kt) {
    const unsigned short* kpt = kp + (size_t)kt * 4096;
    const unsigned short* vpt = vp + (size_t)kt * 4096;
#pragma unroll
    for (int nt = 0; nt < 4; ++nt) {
      kb[nt][0] = *(const s8v*)(kpt + nt * 1024);
      kb[nt][1] = *(const s8v*)(kpt + nt * 1024 + 32);
      vb[nt][0] = *(const s8v*)(vpt + nt * 1024);
      vb[nt][1] = *(const s8v*)(vpt + nt * 1024 + 32);
    }
  };

  auto compute_tile = [&](const s8v (&kb)[4][2], const s8v (&vb)[4][2], int kt) {
    // S^T = K.Q^T: lane holds query=c16 (per half h), keys=nt*16+quad*4+r
    float p[2][4][4];
#pragma unroll
    for (int h = 0; h < 2; ++h)
#pragma unroll
      for (int nt = 0; nt < 4; ++nt) {
        f4v acc = {0.f, 0.f, 0.f, 0.f};
        acc = __builtin_amdgcn_mfma_f32_16x16x32_bf16(kb[nt][0], aq[h][0], acc, 0, 0, 0);
        acc = __builtin_amdgcn_mfma_f32_16x16x32_bf16(kb[nt][1], aq[h][1], acc, 0, 0, 0);
#pragma unroll
        for (int r = 0; r < 4; ++r) p[h][nt][r] = EXP2(acc[r]);  // no-max: f32-safe
      }
    if (kt * 64 + 63 > q0) {  // diagonal tile: zero masked probs
#pragma unroll
      for (int h = 0; h < 2; ++h) {
        const int qmk = q0 + h * 16 + c16 - kt * 64 - quad * 4;
#pragma unroll
        for (int nt = 0; nt < 4; ++nt)
#pragma unroll
          for (int r = 0; r < 4; ++r)
            if (nt * 16 + r > qmk) p[h][nt][r] = 0.f;
      }
    }
#pragma unroll
    for (int h = 0; h < 2; ++h) {
      float s = 0.f;
#pragma unroll
      for (int nt = 0; nt < 4; ++nt)
        s += (p[h][nt][0] + p[h][nt][1]) + (p[h][nt][2] + p[h][nt][3]);
      l[h] += s;
      // P A-frags: pure in-lane pack (sigma ordering); PV with shared sigma
#pragma unroll
      for (int kc = 0; kc < 2; ++kc) {
        union { int d[4]; s8v v; } u;
        u.d[0] = pack_bf2(p[h][2 * kc][0],     p[h][2 * kc][1]);
        u.d[1] = pack_bf2(p[h][2 * kc][2],     p[h][2 * kc][3]);
        u.d[2] = pack_bf2(p[h][2 * kc + 1][0], p[h][2 * kc + 1][1]);
        u.d[3] = pack_bf2(p[h][2 * kc + 1][2], p[h][2 * kc + 1][3]);
#pragma unroll
        for (int dt = 0; dt < 4; ++dt)
          o[h][dt] = __builtin_amdgcn_mfma_f32_16x16x32_bf16(u.v, vb[dt][kc], o[h][dt], 0, 0, 0);
      }
    }
  };

  // ping-pong: loads for tile t+1 in flight while computing tile t
  s8v kA[4][2], vA[4][2], kB[4][2], vB[4][2];
  load_tile(kA, vA, 0);
  int kt = 0;
  for (; kt + 1 < ntiles; kt += 2) {
    load_tile(kB, vB, kt + 1);
    compute_tile(kA, vA, kt);
    if (kt + 2 < ntiles) load_tile(kA, vA, kt + 2);
    compute_tile(kB, vB, kt + 1);
  }
  if (kt < ntiles) compute_tile(kA, vA, kt);

  // ---- epilogue: wave-local ----
#pragma unroll
  for (int h = 0; h < 2; ++h) {
    float lv = l[h];
    lv += __shfl_xor(lv, 16);
    lv += __shfl_xor(lv, 32);     // l(query=c16), replicated over quads
    union { float f; int i; } lu; lu.f = lv;
    float invr[4];
#pragma unroll
    for (int rr = 0; rr < 4; ++rr) {
      union { int i; float f; } tf;
      tf.i = __builtin_amdgcn_ds_bpermute(4 * (quad * 4 + rr), lu.i);
      invr[rr] = 1.0f / tf.f;     // l for my output row quad*4+rr
    }
    if (isF32) {
      float* OF = (float*)Outv;
#pragma unroll
      for (int rr = 0; rr < 4; ++rr) {
        const size_t rb = bh_off + (size_t)(q0 + h * 16 + quad * 4 + rr) * DH + c16;
#pragma unroll
        for (int dt = 0; dt < 4; ++dt)
          OF[rb + dt * 16] = o[h][dt][rr] * invr[rr];
      }
    } else {
      unsigned short* O16 = (unsigned short*)Outv;
#pragma unroll
      for (int rr = 0; rr < 4; ++rr) {
        const size_t rb = bh_off + (size_t)(q0 + h * 16 + quad * 4 + rr) * DH + c16;
#pragma unroll
        for (int dt = 0; dt < 4; ++dt)
          O16[rb + dt * 16] = f2bf(o[h][dt][rr] * invr[rr]);
      }
    }
  }
}

extern "C" void kernel_launch(void* const* d_in, const int* in_sizes, int n_in,
                              void* d_out, int out_size, void* d_ws, size_t ws_size,
                              hipStream_t stream) {
  const void* Q = d_in[0];
  const void* K = d_in[1];
  const void* V = d_in[2];
  unsigned short* Kbf = (unsigned short*)d_ws;                     // 8.39 MB
  unsigned short* Vt  = Kbf + (size_t)BHN * SEQ * DH;              // 8.39 MB

  dim3 g1(SEQ / 64, BHN, 2);
  prep_kernel<<<g1, 256, 0, stream>>>(K, V, Kbf, Vt);
  attn_kernel<<<dim3(2048), 64, 0, stream>>>(Q, Kbf, Vt, d_out);
}

// Round 7
// 138.522 us; speedup vs baseline: 1.4309x; 1.4309x over previous
//
#include <hip/hip_runtime.h>
#include <hip/hip_bf16.h>

// ScaledDotProductAttention B=2,H=16,S=2048,D=64 causal, f32 in/out (probed).
// v17: v10 structure + global_load_lds DMA staging + XOR-swizzled workspace.
// r6 post-mortem: v15's reg ping-pong was defeated by the compiler (VGPR 116,
// not ~230 -> loads serialized; 105us unchanged). The only compiler-proof
// prefetch is global_load_lds (no VGPRs, vmcnt-tracked, drained by the
// existing __syncthreads). v10 (46us) had staging (8 glb->reg + 8 ds_write
// per thread) serial between MFMA-end and barrier -> that's the fat.
//  - attn: exact v10 geometry (1024 blks x 128 thr, quad-balanced qb
//    {7-a,8+a,23-a,24+a}, 4 bh/XCD, dbuf, 1 barrier/iter). Staging = 16
//    global_load_lds_dwordx4 per block-iter (wave0: K 8x1KB, wave1: V).
//  - DMA copies linearly -> LDS keeps 128B row pitch -> frag reads would be
//    16-way conflicts. Fix (rule #21, m201): prep PRE-SWIZZLES the workspace
//    (16B chunk col ^= (row&7)<<4) and attn XORs the same on ds_read.
//    Bank spread: 8 lanes/16B-slot, even -> optimal b128 (matches v10's 72-pitch).
//  - Compute body, mask, sigma PV, no-max exp2 softmax, CSC in Q, epilogue:
//    verbatim v10 (verified).

typedef __attribute__((ext_vector_type(8))) short  s8v;   // 8 x bf16
typedef __attribute__((ext_vector_type(4))) float  f4v;   // MFMA acc
typedef __attribute__((ext_vector_type(4))) unsigned int u4v;

#define SEQ 2048
#define DH  64
#define BHN 32
#define CSC 0.18033688f   // (1/sqrt(64)) * log2(e)

#if __has_builtin(__builtin_amdgcn_exp2f)
#define EXP2(x) __builtin_amdgcn_exp2f(x)
#else
#define EXP2(x) exp2f(x)
#endif

__device__ __forceinline__ unsigned short f2bf(float x) {
  union { float f; unsigned int u; } v; v.f = x;
  return (unsigned short)((v.u + 0x7fffu + ((v.u >> 16) & 1u)) >> 16);  // RNE
}
__device__ __forceinline__ float bf2f(unsigned short x) {
  union { unsigned int u; float f; } v; v.u = ((unsigned int)x) << 16;
  return v.f;
}
__device__ __forceinline__ int pack_bf2(float a, float b) {
  union { __hip_bfloat162 h; int i; } u;
  u.h = __float22bfloat162_rn(make_float2(a, b));   // a->low, b->high
  return u.i;
}
__device__ __forceinline__ bool probe_is_f32(const unsigned short* p) {
  const unsigned e = (p[threadIdx.x & 63] >> 7) & 0xFFu;
  return __ballot(e >= 0x89u) != 0ULL;
}
__device__ __forceinline__ s8v cvt8(const float* p) {
  float4 a = *(const float4*)p;
  float4 b = *(const float4*)(p + 4);
  s8v r;
  r[0] = (short)f2bf(a.x); r[1] = (short)f2bf(a.y);
  r[2] = (short)f2bf(a.z); r[3] = (short)f2bf(a.w);
  r[4] = (short)f2bf(b.x); r[5] = (short)f2bf(b.y);
  r[6] = (short)f2bf(b.z); r[7] = (short)f2bf(b.w);
  return r;
}
__device__ __forceinline__ s8v cvt8s(const float* p, float s) {
  float4 a = *(const float4*)p;
  float4 b = *(const float4*)(p + 4);
  s8v r;
  r[0] = (short)f2bf(a.x * s); r[1] = (short)f2bf(a.y * s);
  r[2] = (short)f2bf(a.z * s); r[3] = (short)f2bf(a.w * s);
  r[4] = (short)f2bf(b.x * s); r[5] = (short)f2bf(b.y * s);
  r[6] = (short)f2bf(b.z * s); r[7] = (short)f2bf(b.w * s);
  return r;
}
__device__ __forceinline__ void gld16(const void* g, void* l) {
  __builtin_amdgcn_global_load_lds(
      (const __attribute__((address_space(1))) void*)g,
      (__attribute__((address_space(3))) void*)l, 16, 0, 0);
}

// ---- pre-pass: z=0 K->bf16 swizzled; z=1 V->Vt chunked + swizzled ----
// Both workspaces: row-major 64-short (128B) rows; within each row the 16B
// chunks are stored at physical col = logical_col ^ ((row&7)<<4).
// Vt logical chunk order (per 64-key tile, row d): chunk c=kc*4+quad holds
// keys {32kc+4quad+0..3, 32kc+16+4quad+0..3} (one 16B PV B-frag).
__global__ __launch_bounds__(256) void prep_kernel(
    const void* __restrict__ Kv, const void* __restrict__ Vv,
    unsigned short* __restrict__ Kbf, unsigned short* __restrict__ Vt) {
  const int bh = blockIdx.y;
  const int s0 = blockIdx.x * 64;
  const int t  = threadIdx.x;
  if (blockIdx.z == 0) {
    const unsigned short* K16 = (const unsigned short*)Kv;
    const float*          KF  = (const float*)Kv;
    const bool isF32 = probe_is_f32(K16);
    const int sr  = t >> 2;
    const int cb0 = (t & 3) * 32;                    // byte col of 1st chunk
    const int xs  = (sr & 7) << 4;
    const size_t src = ((size_t)(bh * SEQ + s0 + sr)) * DH + (t & 3) * 16;
    s8v a0, a1;
    if (!isF32) { a0 = *(const s8v*)(K16 + src); a1 = *(const s8v*)(K16 + src + 8); }
    else        { a0 = cvt8(KF + src);           a1 = cvt8(KF + src + 8); }
    char* rowp = (char*)Kbf + ((size_t)(bh * SEQ + s0 + sr)) * 128;
    *(s8v*)(rowp + (cb0 ^ xs))        = a0;
    *(s8v*)(rowp + ((cb0 + 16) ^ xs)) = a1;
  } else {
    __shared__ __align__(16) unsigned short T[64][72];
    const unsigned short* V16 = (const unsigned short*)Vv;
    const float*          VF  = (const float*)Vv;
    const bool isF32 = probe_is_f32(V16);
    {
      const int sr = t >> 2, c0 = (t & 3) * 16;
      const size_t base = ((size_t)(bh * SEQ + s0 + sr)) * DH + c0;
      s8v a0, a1;
      if (!isF32) { a0 = *(const s8v*)(V16 + base); a1 = *(const s8v*)(V16 + base + 8); }
      else        { a0 = cvt8(VF + base);           a1 = cvt8(VF + base + 8); }
      *(s8v*)&T[sr][c0]     = a0;
      *(s8v*)&T[sr][c0 + 8] = a1;
    }
    __syncthreads();
    {
      const int d  = t & 63;
      const int hs = t >> 6;            // 0..3 -> chunks 2hs, 2hs+1
      const int xs = (d & 7) << 4;
      char* rowp = (char*)Vt + (size_t)bh * SEQ * 128 + (size_t)s0 * 128
                 + (size_t)d * 128;
#pragma unroll
      for (int cc = 0; cc < 2; ++cc) {
        const int c  = hs * 2 + cc;
        const int kA = (c >> 2) * 32 + (c & 3) * 4;  // base key of chunk
        unsigned int wb[4];
        wb[0] = (unsigned int)T[kA + 0][d]  | ((unsigned int)T[kA + 1][d]  << 16);
        wb[1] = (unsigned int)T[kA + 2][d]  | ((unsigned int)T[kA + 3][d]  << 16);
        wb[2] = (unsigned int)T[kA + 16][d] | ((unsigned int)T[kA + 17][d] << 16);
        wb[3] = (unsigned int)T[kA + 18][d] | ((unsigned int)T[kA + 19][d] << 16);
        u4v q = { wb[0], wb[1], wb[2], wb[3] };
        *(u4v*)(rowp + ((c * 16) ^ xs)) = q;
      }
    }
  }
}

// ---- main: flash attention, 64 q-rows/block (2 waves x 32q), 4 blocks/CU,
// DMA-staged double-buffered LDS ----
__global__ __launch_bounds__(128, 2) void attn_kernel(
    const void* __restrict__ Qv, const unsigned short* __restrict__ Kbf,
    const unsigned short* __restrict__ Vt, void* __restrict__ Outv) {
  __shared__ __align__(16) char Lds[2][16384];   // [buf][K 8KB | V 8KB], linear

  const unsigned short* Q16 = (const unsigned short*)Qv;
  const float*          QF  = (const float*)Qv;
  const bool isF32 = probe_is_f32(Q16);

  // decode: xcd=blk&7 (4 bh per XCD L2); qb quad {7-a,8+a,23-a,24+a} sums 66/CU
  const int blk = blockIdx.x;
  const int bh  = (blk & 7) * 4 + ((blk >> 3) & 3);
  const int a   = (blk >> 5) & 7;
  const int bsl = blk >> 8;                            // 0..3
  const int qb  = (bsl == 0) ? (7 - a) : (bsl == 1) ? (8 + a)
                : (bsl == 2) ? (23 - a) : (24 + a);

  const int tid  = threadIdx.x;
  const int w    = tid >> 6;                           // wave 0..1
  const int lane = tid & 63;
  const int quad = lane >> 4;
  const int c16  = lane & 15;
  const int q0   = qb * 64 + w * 32;                   // this wave's 32 q-rows

  const size_t bh_off = (size_t)bh * SEQ * DH;

  // Q fragments: 2 row-halves x 2 k-chunks, prescaled by CSC
  s8v aq[2][2];
#pragma unroll
  for (int h = 0; h < 2; ++h)
#pragma unroll
    for (int kc = 0; kc < 2; ++kc) {
      const size_t idx = bh_off + (size_t)(q0 + h * 16 + c16) * DH + kc * 32 + quad * 8;
      if (isF32) aq[h][kc] = cvt8s(QF + idx, CSC);
      else {
        s8v aa = *(const s8v*)(Q16 + idx);
#pragma unroll
        for (int t = 0; t < 8; ++t)
          aa[t] = (short)f2bf(bf2f((unsigned short)aa[t]) * CSC);
        aq[h][kc] = aa;
      }
    }

  f4v o[2][4];
  float l[2] = {0.f, 0.f};
#pragma unroll
  for (int h = 0; h < 2; ++h)
#pragma unroll
    for (int i = 0; i < 4; ++i) { f4v z = {0.f, 0.f, 0.f, 0.f}; o[h][i] = z; }

  const int ntiles = qb + 1;

  // frag read addressing (swizzled): row*128 + ((kc*64 + quad*16) ^ xorl)
  const int xorl = (c16 & 7) << 4;
  const int fc0  = (quad * 16) ^ xorl;
  const int fc1  = (64 + quad * 16) ^ xorl;
  const int frow = c16 * 128;

  // DMA sources: per-lane 16B of the 8KB tile (tile stride 4096 shorts)
  const unsigned short* Kg = Kbf + bh_off + (size_t)lane * 8;
  const unsigned short* Vg = Vt  + bh_off + (size_t)lane * 8;

  auto stage = [&](int tile, int buf) {
    if (w == 0) {
      const unsigned short* g = Kg + (size_t)tile * 4096;
      char* lp = &Lds[buf][0];
#pragma unroll
      for (int j = 0; j < 8; ++j) gld16(g + j * 512, lp + j * 1024);
    } else {
      const unsigned short* g = Vg + (size_t)tile * 4096;
      char* lp = &Lds[buf][8192];
#pragma unroll
      for (int j = 0; j < 8; ++j) gld16(g + j * 512, lp + j * 1024);
    }
  };

  stage(0, 0);          // prologue: DMA tile 0 into buf 0
  __syncthreads();      // drains vmcnt -> tile 0 resident

  for (int kt = 0; kt < ntiles; ++kt) {
    const int cb = kt & 1, nb = cb ^ 1;
    if (kt + 1 < ntiles) stage(kt + 1, nb);   // fire-and-forget DMA

    const char* Kl = &Lds[cb][0];
    const char* Vl = &Lds[cb][8192];
    s8v kb[4][2], vb[4][2];
#pragma unroll
    for (int nt = 0; nt < 4; ++nt) {
      kb[nt][0] = *(const s8v*)(Kl + frow + nt * 2048 + fc0);
      kb[nt][1] = *(const s8v*)(Kl + frow + nt * 2048 + fc1);
      vb[nt][0] = *(const s8v*)(Vl + frow + nt * 2048 + fc0);
      vb[nt][1] = *(const s8v*)(Vl + frow + nt * 2048 + fc1);
    }

    __builtin_amdgcn_s_setprio(1);
    // S^T = K.Q^T: lane holds query=c16 (per half h), keys=nt*16+quad*4+r
    float p[2][4][4];
#pragma unroll
    for (int h = 0; h < 2; ++h)
#pragma unroll
      for (int nt = 0; nt < 4; ++nt) {
        f4v acc = {0.f, 0.f, 0.f, 0.f};
        acc = __builtin_amdgcn_mfma_f32_16x16x32_bf16(kb[nt][0], aq[h][0], acc, 0, 0, 0);
        acc = __builtin_amdgcn_mfma_f32_16x16x32_bf16(kb[nt][1], aq[h][1], acc, 0, 0, 0);
#pragma unroll
        for (int r = 0; r < 4; ++r) p[h][nt][r] = EXP2(acc[r]);  // no-max: f32-safe
      }
    if (kt * 64 + 63 > q0) {  // diagonal tile: zero masked probs
#pragma unroll
      for (int h = 0; h < 2; ++h) {
        const int qmk = q0 + h * 16 + c16 - kt * 64 - quad * 4;
#pragma unroll
        for (int nt = 0; nt < 4; ++nt)
#pragma unroll
          for (int r = 0; r < 4; ++r)
            if (nt * 16 + r > qmk) p[h][nt][r] = 0.f;
      }
    }
#pragma unroll
    for (int h = 0; h < 2; ++h) {
      float s = 0.f;
#pragma unroll
      for (int nt = 0; nt < 4; ++nt)
        s += (p[h][nt][0] + p[h][nt][1]) + (p[h][nt][2] + p[h][nt][3]);
      l[h] += s;
      // P A-frags: pure in-lane pack (sigma ordering); PV with shared sigma
#pragma unroll
      for (int kc = 0; kc < 2; ++kc) {
        union { int d[4]; s8v v; } u;
        u.d[0] = pack_bf2(p[h][2 * kc][0],     p[h][2 * kc][1]);
        u.d[1] = pack_bf2(p[h][2 * kc][2],     p[h][2 * kc][3]);
        u.d[2] = pack_bf2(p[h][2 * kc + 1][0], p[h][2 * kc + 1][1]);
        u.d[3] = pack_bf2(p[h][2 * kc + 1][2], p[h][2 * kc + 1][3]);
#pragma unroll
        for (int dt = 0; dt < 4; ++dt)
          o[h][dt] = __builtin_amdgcn_mfma_f32_16x16x32_bf16(u.v, vb[dt][kc], o[h][dt], 0, 0, 0);
      }
    }
    __builtin_amdgcn_s_setprio(0);

    __syncthreads();   // drains this wave's DMA vmcnt + LDS reads; buffers flip
  }

  // ---- epilogue: wave-local, per row-half ----
#pragma unroll
  for (int h = 0; h < 2; ++h) {
    float lv = l[h];
    lv += __shfl_xor(lv, 16);
    lv += __shfl_xor(lv, 32);     // l(query=c16), replicated over quads
    union { float f; int i; } lu; lu.f = lv;
    float invr[4];
#pragma unroll
    for (int rr = 0; rr < 4; ++rr) {
      union { int i; float f; } tf;
      tf.i = __builtin_amdgcn_ds_bpermute(4 * (quad * 4 + rr), lu.i);
      invr[rr] = 1.0f / tf.f;     // l for my output row quad*4+rr
    }
    if (isF32) {
      float* OF = (float*)Outv;
#pragma unroll
      for (int rr = 0; rr < 4; ++rr) {
        const size_t rb = bh_off + (size_t)(q0 + h * 16 + quad * 4 + rr) * DH + c16;
#pragma unroll
        for (int dt = 0; dt < 4; ++dt)
          OF[rb + dt * 16] = o[h][dt][rr] * invr[rr];
      }
    } else {
      unsigned short* O16 = (unsigned short*)Outv;
#pragma unroll
      for (int rr = 0; rr < 4; ++rr) {
        const size_t rb = bh_off + (size_t)(q0 + h * 16 + quad * 4 + rr) * DH + c16;
#pragma unroll
        for (int dt = 0; dt < 4; ++dt)
          O16[rb + dt * 16] = f2bf(o[h][dt][rr] * invr[rr]);
      }
    }
  }
}

extern "C" void kernel_launch(void* const* d_in, const int* in_sizes, int n_in,
                              void* d_out, int out_size, void* d_ws, size_t ws_size,
                              hipStream_t stream) {
  const void* Q = d_in[0];
  const void* K = d_in[1];
  const void* V = d_in[2];
  unsigned short* Kbf = (unsigned short*)d_ws;                     // 8.39 MB
  unsigned short* Vt  = Kbf + (size_t)BHN * SEQ * DH;              // 8.39 MB

  dim3 g1(SEQ / 64, BHN, 2);
  prep_kernel<<<g1, 256, 0, stream>>>(K, V, Kbf, Vt);
  attn_kernel<<<dim3(1024), 128, 0, stream>>>(Q, Kbf, Vt, d_out);
}